// Round 17
// baseline (603.082 us; speedup 1.0000x reference)
//
#include <hip/hip_runtime.h>
#include <hip/hip_bf16.h>
#include <math.h>

#define NROWS 25600
#define SEQL  25
#define EPSV  1e-6f

typedef __hip_bfloat16 bf16;
typedef __attribute__((ext_vector_type(4))) float f32x4;
typedef __attribute__((ext_vector_type(8))) short bf16x8;
typedef __attribute__((ext_vector_type(4))) short s16x4;
typedef unsigned int u32;

#define GLD16(gp_, lp_) __builtin_amdgcn_global_load_lds( \
    (const __attribute__((address_space(1))) u32*)(gp_), \
    (__attribute__((address_space(3))) u32*)(lp_), 16, 0, 0)

__device__ __forceinline__ float b2f(short s) {
  return __uint_as_float(((u32)(unsigned short)s) << 16);
}
__device__ __forceinline__ short f2b(float f) {
  __hip_bfloat16 h = __float2bfloat16(f);
  return *reinterpret_cast<short*>(&h);
}

// ---------------- Cl(3,0) geometric product (fp32) --------------------------
__device__ __forceinline__ void gprod(const float* a, const float* b, float* r) {
  const int M[8] = {0,1,2,4,3,5,6,7};
  const int P[8] = {0,1,2,4,3,5,6,7};
#pragma unroll
  for (int i = 0; i < 8; ++i) {
    const int ma = M[i];
#pragma unroll
    for (int k = 0; k < 8; ++k) {
      const int mb = M[k];
      int par = 0;
      for (int t = ma >> 1; t; t >>= 1) par += __popc(t & mb);
      const float s = (par & 1) ? -1.f : 1.f;
      r[P[ma ^ mb]] += s * a[i] * b[k];
    }
  }
}

// ---------------- gemm11: A staged ONCE, loop over output col-tiles ---------
// A planar [8][NROWS][KT]; W [4 grades][ONW][KT] bf16 (LN fold applied).
// Block = (64-row tile x, plane z). Stage A once (64xKT); loop NCOL col-tiles:
// stage W-tile (64xKT, L2-hot, single buffer; latency hidden under previous
// col-step's C write-out), 4*NC ks-steps of 2x2 MFMA, LDS-staged coalesced
// epilogue (round-15 proven, pitch 84). Routing per ct: buffer Y[ct>>1],
// col = yc[ct>>1] + (ct&1)*64. y = acc*invnm[n] + bias[ct*64+col] (plane 0).
struct G11 {
  const bf16* A; const bf16* W; const float* bias; const float* invnm;
  bf16* Y0; bf16* Y1; bf16* Y2; bf16* Y3;
  int yc0, yc1, yc2, yc3; int ONW; int ONS;
};

#define OPITCH 84

template<int KT, int NCOL>
__global__ __launch_bounds__(256) void gemm11_kernel(G11 P)
{
  constexpr int NC = KT / 128;
  __shared__ __align__(16) short As[64 * KT];
  __shared__ __align__(16) short Ws[64 * KT];
  __shared__ __align__(16) short Cs[64 * OPITCH];
  const int tid  = threadIdx.x;
  const int lane = tid & 63;
  const int wid  = tid >> 6;
  const int z    = blockIdx.z;
  const int g    = (z == 0) ? 0 : ((z < 4) ? 1 : ((z < 7) ? 2 : 3));
  const size_t n0 = (size_t)blockIdx.x * 64;
  const bf16* Ab = P.A + (size_t)z * NROWS * KT + n0 * KT;
  const int wm  = (wid & 1) * 32;
  const int wn  = (wid >> 1) * 32;
  const int lg  = lane >> 4;
  const int l15 = lane & 15;

  auto STAGEW = [&](int ct) {
    const bf16* Wb = P.W + ((size_t)g * P.ONW + ct * 64) * KT;
#pragma unroll
    for (int kc = 0; kc < NC; ++kc)
#pragma unroll
      for (int j = 0; j < 4; ++j) {
        const int row = wid * 16 + j * 4 + lg;
        const int sw = (l15 ^ (row & 7)) * 8;
        GLD16(Wb + (size_t)row * KT + kc * 128 + sw, &Ws[kc * 8192 + wid * 2048 + j * 512]);
      }
  };

  // stage A once (64 x KT) + first W tile
#pragma unroll
  for (int kc = 0; kc < NC; ++kc)
#pragma unroll
    for (int j = 0; j < 4; ++j) {
      const int row = wid * 16 + j * 4 + lg;
      const int sw = (l15 ^ (row & 7)) * 8;
      GLD16(Ab + (size_t)row * KT + kc * 128 + sw, &As[kc * 8192 + wid * 2048 + j * 512]);
    }
  STAGEW(0);
  __syncthreads();

#pragma unroll
  for (int ct = 0; ct < NCOL; ++ct) {
    // ---- compute 64x64 tile from retained A + current W ----
    f32x4 acc[2][2];
#pragma unroll
    for (int i = 0; i < 2; ++i)
#pragma unroll
      for (int j = 0; j < 2; ++j) acc[i][j] = (f32x4){0.f, 0.f, 0.f, 0.f};
#pragma unroll
    for (int kc = 0; kc < NC; ++kc) {
#pragma unroll
      for (int ks = 0; ks < 4; ++ks) {
        bf16x8 af[2], bg[2];
#pragma unroll
        for (int i = 0; i < 2; ++i) {
          const int rA = wm + i * 16 + l15;
          const int rB = wn + i * 16 + l15;
          af[i] = *(const bf16x8*)&As[kc * 8192 + rA * 128 + (((ks * 4 + lg) ^ (rA & 7)) * 8)];
          bg[i] = *(const bf16x8*)&Ws[kc * 8192 + rB * 128 + (((ks * 4 + lg) ^ (rB & 7)) * 8)];
        }
#pragma unroll
        for (int mi = 0; mi < 2; ++mi)
#pragma unroll
          for (int ni = 0; ni < 2; ++ni)
            acc[mi][ni] = __builtin_amdgcn_mfma_f32_16x16x32_bf16(af[mi], bg[ni], acc[mi][ni], 0, 0, 0);
      }
    }

    // ---- stage C tile into Cs (scale/bias applied) ----
    const int cr = lg * 4;
#pragma unroll
    for (int mi = 0; mi < 2; ++mi) {
#pragma unroll
      for (int j = 0; j < 4; ++j) {
        const int r = wm + mi * 16 + cr + j;
        const size_t n = n0 + r;
        const float sc = P.invnm ? P.invnm[n] : 1.f;
#pragma unroll
        for (int ni = 0; ni < 2; ++ni) {
          const int cl = wn + ni * 16 + l15;
          float v = acc[mi][ni][j] * sc;
          if (z == 0) v += P.bias[ct * 64 + cl];
          Cs[r * OPITCH + cl] = f2b(v);
        }
      }
    }
    __syncthreads();   // C visible; all waves done reading Ws[ct]

    // prefetch next W tile (flies under the C write-out below)
    if (ct + 1 < NCOL) STAGEW(ct + 1);

    // ---- coalesced C write-out (routing for this ct) ----
    const int bufi = ct >> 1;
    bf16* Yb; int yc;
    if      (bufi == 0) { Yb = P.Y0; yc = P.yc0; }
    else if (bufi == 1) { Yb = P.Y1; yc = P.yc1; }
    else if (bufi == 2) { Yb = P.Y2; yc = P.yc2; }
    else                { Yb = P.Y3; yc = P.yc3; }
    yc += (ct & 1) * 64;
    bf16* Yp = Yb + (size_t)z * NROWS * P.ONS + yc;
    const int wrow = tid >> 3;        // 0..31
    const int wcol = (tid & 7) * 8;   // 8 cols per thread (16B)
#pragma unroll
    for (int rr = 0; rr < 2; ++rr) {
      const int row = rr * 32 + wrow;
      const s16x4 lo = *(const s16x4*)&Cs[row * OPITCH + wcol];
      const s16x4 hi = *(const s16x4*)&Cs[row * OPITCH + wcol + 4];
      *(s16x4*)(Yp + (size_t)(n0 + row) * P.ONS + wcol) = lo;
      *(s16x4*)(Yp + (size_t)(n0 + row) * P.ONS + wcol + 4) = hi;
    }
    __syncthreads();   // W[ct+1] drained; Cs free for next col-step
  }
}

// ---------------- weight prep: combined planar bf16 weights -----------------
__global__ __launch_bounds__(256) void wprep_all_kernel(
    const float* wq, const float* wk, const float* wv, const float* wo,
    const float* gw1, const float* gw2, const float* gw3,
    const float* mw1, const float* mw2,
    const float* ln1, const float* ln2, const float* ln3,
    bf16* WQKV, bf16* WO, bf16* WG12, bf16* WG3, bf16* WM1, bf16* WM2)
{
  const int gid = blockIdx.x * 256 + threadIdx.x;
  const float* w; const float* ln; bf16* out; int K; int idx; int planeSz; int rowOfs;
  if      (gid <  16384) { w=wq;  ln=ln1;     out=WQKV; K=128; idx=gid;        planeSz=49152; rowOfs=0;   }
  else if (gid <  32768) { w=wk;  ln=ln1;     out=WQKV; K=128; idx=gid-16384;  planeSz=49152; rowOfs=128; }
  else if (gid <  49152) { w=wv;  ln=ln1;     out=WQKV; K=128; idx=gid-32768;  planeSz=49152; rowOfs=256; }
  else if (gid <  65536) { w=wo;  ln=nullptr; out=WO;   K=128; idx=gid-49152;  planeSz=16384; rowOfs=0;   }
  else if (gid <  98304) { w=gw1; ln=ln2;     out=WG12; K=128; idx=gid-65536;  planeSz=65536; rowOfs=0;   }
  else if (gid < 131072) { w=gw2; ln=ln2;     out=WG12; K=128; idx=gid-98304;  planeSz=65536; rowOfs=256; }
  else if (gid < 163840) { w=gw3; ln=nullptr; out=WG3;  K=256; idx=gid-131072; planeSz=32768; rowOfs=0;   }
  else if (gid < 196608) { w=mw1; ln=ln3;     out=WM1;  K=128; idx=gid-163840; planeSz=32768; rowOfs=0;   }
  else                   { w=mw2; ln=nullptr; out=WM2;  K=256; idx=gid-196608; planeSz=32768; rowOfs=0;   }
  const int k = idx % K;
  const float s = ln ? ln[k] : 1.f;
  const float4 wv4 = *(const float4*)(w + (size_t)idx * 4);
  bf16* dst = out + (size_t)rowOfs * K + idx;
  dst[0 * planeSz] = __float2bfloat16(wv4.x * s);
  dst[1 * planeSz] = __float2bfloat16(wv4.y * s);
  dst[2 * planeSz] = __float2bfloat16(wv4.z * s);
  dst[3 * planeSz] = __float2bfloat16(wv4.w * s);
}

// ---------------- combined bias buffers -------------------------------------
__global__ __launch_bounds__(256) void bias_prep_kernel(
    const float* bq, const float* bk, const float* bv,
    const float* gb1, const float* gb2,
    float* BQKV, float* BG12)
{
  const int t = blockIdx.x * 256 + threadIdx.x;
  if      (t < 128) BQKV[t] = bq[t];
  else if (t < 256) BQKV[t] = bk[t - 128];
  else if (t < 384) BQKV[t] = bv[t - 256];
  else if (t < 640) BG12[t - 384] = gb1[t - 384];
  else if (t < 896) BG12[t - 384] = gb2[t - 640];
}

// ---------------- repack: src f32 [n][128][8] -> Xp bf16 planar + 1/nm1 -----
__global__ __launch_bounds__(256) void repack_kernel(
    const float* __restrict__ src, bf16* __restrict__ Xp, float* __restrict__ nminv)
{
  const int tid = threadIdx.x;
  const size_t base = ((size_t)blockIdx.x * 256 + tid) * 4;
  const size_t P = (size_t)NROWS * 128;
  float v[4][8];
  const float4* sp = (const float4*)(src + base * 8);
  float part = 0.f;
#pragma unroll
  for (int e = 0; e < 4; ++e) {
    const float4 a = sp[e * 2], b = sp[e * 2 + 1];
    v[e][0]=a.x; v[e][1]=a.y; v[e][2]=a.z; v[e][3]=a.w;
    v[e][4]=b.x; v[e][5]=b.y; v[e][6]=b.z; v[e][7]=b.w;
    float ss = 0.f;
#pragma unroll
    for (int p = 0; p < 8; ++p) ss += v[e][p] * v[e][p];
    part += sqrtf(ss);
  }
#pragma unroll
  for (int p = 0; p < 8; ++p) {
    s16x4 o;
#pragma unroll
    for (int e = 0; e < 4; ++e) o[e] = f2b(v[e][p]);
    *(s16x4*)(Xp + p * P + base) = o;
  }
#pragma unroll
  for (int off = 1; off < 32; off <<= 1) part += __shfl_xor(part, off);
  if ((tid & 31) == 0) nminv[base >> 7] = 1.f / (part / 128.f + EPSV);
}

// ---------------- attention: 1 wave per (b,h); MFMA QK^T, in-reg softmax ----
__global__ __launch_bounds__(256) void attn_kernel(
    bf16* __restrict__ Q, const bf16* __restrict__ K, const bf16* __restrict__ V)
{
  __shared__ float Pld[4][32 * 36];
  const int tid  = threadIdx.x;
  const int lane = tid & 63;
  const int wid  = tid >> 6;
  const int job  = blockIdx.x * 4 + wid;
  const int b    = job >> 3;
  const int h    = job & 7;
  const size_t PS = (size_t)NROWS * 128;
  const int rowbase = b * SEQL;
  const int l15 = lane & 15;
  const int lg  = lane >> 4;

  f32x4 acc[2][2];
#pragma unroll
  for (int si = 0; si < 2; ++si)
#pragma unroll
    for (int ti = 0; ti < 2; ++ti) acc[si][ti] = (f32x4){0.f,0.f,0.f,0.f};

#pragma unroll
  for (int ks = 0; ks < 4; ++ks) {
    const int f = ks * 32 + lg * 8;
    const int p = f >> 4, d = f & 15;
    bf16x8 aq[2], bk[2];
#pragma unroll
    for (int si = 0; si < 2; ++si) {
      int s = si * 16 + l15; if (s > 24) s = 24;
      aq[si] = *(const bf16x8*)(Q + (size_t)p * PS + (size_t)(rowbase + s) * 128 + h * 16 + d);
    }
#pragma unroll
    for (int ti = 0; ti < 2; ++ti) {
      int t = ti * 16 + l15; if (t > 24) t = 24;
      bk[ti] = *(const bf16x8*)(K + (size_t)p * PS + (size_t)(rowbase + t) * 128 + h * 16 + d);
    }
#pragma unroll
    for (int si = 0; si < 2; ++si)
#pragma unroll
      for (int ti = 0; ti < 2; ++ti)
        acc[si][ti] = __builtin_amdgcn_mfma_f32_16x16x32_bf16(aq[si], bk[ti], acc[si][ti], 0, 0, 0);
  }

  const float scale = 0.08838834764831845f;
  float pv[2][2][4];
#pragma unroll
  for (int si = 0; si < 2; ++si)
#pragma unroll
    for (int ti = 0; ti < 2; ++ti)
#pragma unroll
      for (int r = 0; r < 4; ++r) {
        float v = acc[si][ti][r] * scale;
        if (ti * 16 + l15 > 24) v = -1e30f;
        pv[si][ti][r] = v;
      }
#pragma unroll
  for (int si = 0; si < 2; ++si)
#pragma unroll
    for (int r = 0; r < 4; ++r) {
      float m = fmaxf(pv[si][0][r], pv[si][1][r]);
#pragma unroll
      for (int off = 1; off < 16; off <<= 1) m = fmaxf(m, __shfl_xor(m, off));
      const float e0 = __expf(pv[si][0][r] - m);
      const float e1 = __expf(pv[si][1][r] - m);
      float sum = e0 + e1;
#pragma unroll
      for (int off = 1; off < 16; off <<= 1) sum += __shfl_xor(sum, off);
      const float inv = 1.f / sum;
      pv[si][0][r] = e0 * inv;
      pv[si][1][r] = e1 * inv;
    }

  float* Pw = &Pld[wid][0];
#pragma unroll
  for (int si = 0; si < 2; ++si)
#pragma unroll
    for (int ti = 0; ti < 2; ++ti)
#pragma unroll
      for (int r = 0; r < 4; ++r)
        Pw[(si * 16 + lg * 4 + r) * 36 + ti * 16 + l15] = pv[si][ti][r];
  __syncthreads();

  const int p2 = lane >> 3;
  const int d2 = (lane & 7) * 2;
  const bf16* vb = V + (size_t)p2 * PS + (size_t)rowbase * 128 + h * 16 + d2;
  float vlo[32], vhi[32];
#pragma unroll
  for (int t = 0; t < SEQL; ++t) {
    const __hip_bfloat162 vv = *(const __hip_bfloat162*)(vb + (size_t)t * 128);
    vlo[t] = __bfloat162float(vv.x);
    vhi[t] = __bfloat162float(vv.y);
  }
#pragma unroll
  for (int t = SEQL; t < 32; ++t) { vlo[t] = 0.f; vhi[t] = 0.f; }

  bf16* ob = Q + (size_t)p2 * PS + (size_t)rowbase * 128 + h * 16 + d2;
  for (int s = 0; s < SEQL; ++s) {
    const float4* pr = reinterpret_cast<const float4*>(&Pld[wid][s * 36]);
    float a0 = 0.f, a1 = 0.f;
#pragma unroll
    for (int t4 = 0; t4 < 8; ++t4) {
      const float4 pq = pr[t4];
      a0 += pq.x * vlo[t4*4+0] + pq.y * vlo[t4*4+1] + pq.z * vlo[t4*4+2] + pq.w * vlo[t4*4+3];
      a1 += pq.x * vhi[t4*4+0] + pq.y * vhi[t4*4+1] + pq.z * vhi[t4*4+2] + pq.w * vhi[t4*4+3];
    }
    __hip_bfloat162 o2;
    o2.x = __float2bfloat16(a0);
    o2.y = __float2bfloat16(a1);
    *(__hip_bfloat162*)(ob + (size_t)s * 128) = o2;
  }
}

// ---------------- xres = src + AO (4-wide) + 1/nm2 --------------------------
__global__ __launch_bounds__(256) void xres_kernel(
    const float* __restrict__ src, const bf16* __restrict__ AO,
    bf16* __restrict__ X, float* __restrict__ nminv)
{
  const int tid = threadIdx.x;
  const size_t base = ((size_t)blockIdx.x * 256 + tid) * 4;
  const size_t P = (size_t)NROWS * 128;
  float v[4][8];
  const float4* sp = (const float4*)(src + base * 8);
#pragma unroll
  for (int e = 0; e < 4; ++e) {
    const float4 a = sp[e * 2], b = sp[e * 2 + 1];
    v[e][0]=a.x; v[e][1]=a.y; v[e][2]=a.z; v[e][3]=a.w;
    v[e][4]=b.x; v[e][5]=b.y; v[e][6]=b.z; v[e][7]=b.w;
  }
  float part = 0.f;
  float ss[4] = {0.f, 0.f, 0.f, 0.f};
#pragma unroll
  for (int p = 0; p < 8; ++p) {
    const s16x4 av = *(const s16x4*)(AO + p * P + base);
    s16x4 o;
#pragma unroll
    for (int e = 0; e < 4; ++e) {
      v[e][p] += b2f(av[e]);
      o[e] = f2b(v[e][p]);
      ss[e] += v[e][p] * v[e][p];
    }
    *(s16x4*)(X + p * P + base) = o;
  }
#pragma unroll
  for (int e = 0; e < 4; ++e) part += sqrtf(ss[e]);
#pragma unroll
  for (int off = 1; off < 32; off <<= 1) part += __shfl_xor(part, off);
  if ((tid & 31) == 0) nminv[base >> 7] = 1.f / (part / 128.f + EPSV);
}

// ---------------- GP elementwise (4-wide, in place over XL) -----------------
__global__ __launch_bounds__(256) void gp_kernel(
    bf16* __restrict__ XL, const bf16* __restrict__ XR)
{
  const size_t base = ((size_t)blockIdx.x * 256 + threadIdx.x) * 4;
  const size_t P = (size_t)NROWS * 256;
  s16x4 av[8], bv[8], rv[8];
#pragma unroll
  for (int p = 0; p < 8; ++p) {
    av[p] = *(const s16x4*)(XL + p * P + base);
    bv[p] = *(const s16x4*)(XR + p * P + base);
  }
#pragma unroll
  for (int e = 0; e < 4; ++e) {
    float a[8], b[8], r[8] = {0.f,0.f,0.f,0.f,0.f,0.f,0.f,0.f};
#pragma unroll
    for (int p = 0; p < 8; ++p) { a[p] = b2f(av[p][e]); b[p] = b2f(bv[p][e]); }
    gprod(a, b, r);
#pragma unroll
    for (int p = 0; p < 8; ++p) rv[p][e] = f2b(r[p]);
  }
#pragma unroll
  for (int p = 0; p < 8; ++p) *(s16x4*)(XL + p * P + base) = rv[p];
}

// ---- x3 = ln2a*Xres/nm2 + gna*Gl/nmg (4-wide, shfl norms, in place) --------
__global__ __launch_bounds__(256) void combine_kernel(
    bf16* __restrict__ X, const bf16* __restrict__ Gl,
    const float* __restrict__ ln2a, const float* __restrict__ gna,
    const float* __restrict__ nm2inv, float* __restrict__ nm4inv)
{
  const int tid = threadIdx.x;
  const size_t base = ((size_t)blockIdx.x * 256 + tid) * 4;
  const size_t P = (size_t)NROWS * 128;
  const size_t n = base >> 7;
  const int c = (int)(base & 127);

  float gv[4][8];
  float ssg[4] = {0.f,0.f,0.f,0.f};
#pragma unroll
  for (int p = 0; p < 8; ++p) {
    const s16x4 g4 = *(const s16x4*)(Gl + p * P + base);
#pragma unroll
    for (int e = 0; e < 4; ++e) { gv[e][p] = b2f(g4[e]); ssg[e] += gv[e][p] * gv[e][p]; }
  }
  float partg = sqrtf(ssg[0]) + sqrtf(ssg[1]) + sqrtf(ssg[2]) + sqrtf(ssg[3]);
#pragma unroll
  for (int off = 1; off < 32; off <<= 1) partg += __shfl_xor(partg, off);
  const float invg = 1.f / (partg / 128.f + EPSV);

  const float n2 = nm2inv[n];
  float s2[4], sg[4];
#pragma unroll
  for (int e = 0; e < 4; ++e) { s2[e] = ln2a[c + e] * n2; sg[e] = gna[c + e] * invg; }

  float ss[4] = {0.f,0.f,0.f,0.f};
#pragma unroll
  for (int p = 0; p < 8; ++p) {
    const s16x4 x4 = *(const s16x4*)(X + p * P + base);
    s16x4 o;
#pragma unroll
    for (int e = 0; e < 4; ++e) {
      const float v = s2[e] * b2f(x4[e]) + sg[e] * gv[e][p];
      o[e] = f2b(v);
      ss[e] += v * v;
    }
    *(s16x4*)(X + p * P + base) = o;
  }
  float part = sqrtf(ss[0]) + sqrtf(ss[1]) + sqrtf(ss[2]) + sqrtf(ss[3]);
#pragma unroll
  for (int off = 1; off < 32; off <<= 1) part += __shfl_xor(part, off);
  if ((tid & 31) == 0) nm4inv[n] = 1.f / (part / 128.f + EPSV);
}

// ---------------- MVSiLU (4-wide, in place) ---------------------------------
__global__ __launch_bounds__(256) void silu_kernel(
    bf16* __restrict__ H, const float* __restrict__ sa, const float* __restrict__ sb)
{
  const size_t base = ((size_t)blockIdx.x * 256 + threadIdx.x) * 4;
  const int c = (int)(base & 255);
  const size_t P = (size_t)NROWS * 256;
  s16x4 hv[8];
#pragma unroll
  for (int p = 0; p < 8; ++p) hv[p] = *(const s16x4*)(H + p * P + base);
#pragma unroll
  for (int e = 0; e < 4; ++e) {
    float v[8];
#pragma unroll
    for (int p = 0; p < 8; ++p) v[p] = b2f(hv[p][e]);
    const float i0 = v[0];
    const float i1 = v[1]*v[1] + v[2]*v[2] + v[3]*v[3];
    const float i2 = v[4]*v[4] + v[5]*v[5] + v[6]*v[6];
    const float i3 = v[7]*v[7];
    const int cc = c + e;
    const float g0 = 1.f / (1.f + __expf(-(sa[cc*4+0]*i0 + sb[cc*4+0])));
    const float g1 = 1.f / (1.f + __expf(-(sa[cc*4+1]*i1 + sb[cc*4+1])));
    const float g2 = 1.f / (1.f + __expf(-(sa[cc*4+2]*i2 + sb[cc*4+2])));
    const float g3 = 1.f / (1.f + __expf(-(sa[cc*4+3]*i3 + sb[cc*4+3])));
    v[0]*=g0; v[1]*=g1; v[2]*=g1; v[3]*=g1; v[4]*=g2; v[5]*=g2; v[6]*=g2; v[7]*=g3;
#pragma unroll
    for (int p = 0; p < 8; ++p) hv[p][e] = f2b(v[p]);
  }
#pragma unroll
  for (int p = 0; p < 8; ++p) *(s16x4*)(H + p * P + base) = hv[p];
}

// ---------------- final: out = ln3a*X3/nm4 + FF (4-wide, coalesced) ---------
__global__ __launch_bounds__(256) void final_kernel(
    const bf16* __restrict__ X3, const bf16* __restrict__ FF,
    const float* __restrict__ ln3a, const float* __restrict__ nm4inv,
    float* __restrict__ out)
{
  const size_t base = ((size_t)blockIdx.x * 256 + threadIdx.x) * 4;
  const int c = (int)(base & 127);
  const size_t n = base >> 7;
  const size_t P = (size_t)NROWS * 128;
  const float nm = nm4inv[n];
  float o[4][8];
#pragma unroll
  for (int p = 0; p < 8; ++p) {
    const s16x4 x4 = *(const s16x4*)(X3 + p * P + base);
    const s16x4 f4 = *(const s16x4*)(FF + p * P + base);
#pragma unroll
    for (int e = 0; e < 4; ++e)
      o[e][p] = ln3a[c + e] * nm * b2f(x4[e]) + b2f(f4[e]);
  }
  float4* op = (float4*)(out + base * 8);
#pragma unroll
  for (int e = 0; e < 4; ++e) {
    float4 lo, hi;
    lo.x=o[e][0]; lo.y=o[e][1]; lo.z=o[e][2]; lo.w=o[e][3];
    hi.x=o[e][4]; hi.y=o[e][5]; hi.z=o[e][6]; hi.w=o[e][7];
    op[e * 2] = lo;
    op[e * 2 + 1] = hi;
  }
}

// ---------------- launch ----------------------------------------------------
extern "C" void kernel_launch(void* const* d_in, const int* in_sizes, int n_in,
                              void* d_out, int out_size, void* d_ws, size_t ws_size,
                              hipStream_t stream) {
  (void)in_sizes; (void)n_in; (void)out_size; (void)ws_size;
  const float* src   = (const float*)d_in[0];
  const float* ln1_a = (const float*)d_in[1];
  const float* ln2_a = (const float*)d_in[2];
  const float* ln3_a = (const float*)d_in[3];
  const float* wq = (const float*)d_in[4];  const float* bq = (const float*)d_in[5];
  const float* wk = (const float*)d_in[6];  const float* bk = (const float*)d_in[7];
  const float* wv = (const float*)d_in[8];  const float* bv = (const float*)d_in[9];
  const float* wo = (const float*)d_in[10]; const float* bo = (const float*)d_in[11];
  const float* gw1 = (const float*)d_in[12]; const float* gb1 = (const float*)d_in[13];
  const float* gw2 = (const float*)d_in[14]; const float* gb2 = (const float*)d_in[15];
  const float* gw3 = (const float*)d_in[16]; const float* gb3 = (const float*)d_in[17];
  const float* gna = (const float*)d_in[18];
  const float* mw1 = (const float*)d_in[19]; const float* mb1 = (const float*)d_in[20];
  const float* sa  = (const float*)d_in[21]; const float* sb  = (const float*)d_in[22];
  const float* mw2 = (const float*)d_in[23]; const float* mb2 = (const float*)d_in[24];

  char* ws = (char*)d_ws;
  const size_t P128 = (size_t)NROWS * 128;
  const size_t PSET = 8 * P128;               // one full [8][N][128] plane-set
  bf16* R1 = (bf16*)ws;                       // 104,857,600 B = 2 plane-sets
  bf16* R2 = (bf16*)(ws + 104857600);         //  52,428,800 B = 1 plane-set
  bf16* WQKV = (bf16*)(ws + 157286400);       // [4][384][128]
  bf16* WO   = WQKV + 196608;                 // [4][128][128]
  bf16* WG12 = WO   + 65536;                  // [4][512][128]
  bf16* WG3  = WG12 + 262144;                 // [4][128][256]
  bf16* WM1  = WG3  + 131072;                 // [4][256][128]
  bf16* WM2  = WM1  + 131072;                 // [4][128][256]
  float* BQKV = (float*)(ws + 159121408);     // 384
  float* BG12 = BQKV + 384;                   // 512
  float* nm1  = BG12 + 512;
  float* nm2  = nm1 + NROWS;
  float* nm4  = nm2 + NROWS;

  bf16* Dd = (bf16*)d_out;   // scratch: Q/O, then XL/GP/H; final fp32 out
  bf16* Kb = R1;             // K plane-set
  bf16* Vb = R1 + PSET;      // V plane-set (disjoint)

  wprep_all_kernel<<<896, 256, 0, stream>>>(
      wq, wk, wv, wo, gw1, gw2, gw3, mw1, mw2, ln1_a, ln2_a, ln3_a,
      WQKV, WO, WG12, WG3, WM1, WM2);
  bias_prep_kernel<<<4, 256, 0, stream>>>(bq, bk, bv, gb1, gb2, BQKV, BG12);

  // repack src -> Xp (R2) + 1/nm1
  repack_kernel<<<3200, 256, 0, stream>>>(src, R2, nm1);

  G11 P{};
  // QKV one dispatch: ct 0-1 -> Q(Dd), 2-3 -> K(Kb), 4-5 -> V(Vb)
  P = G11{R2, WQKV, BQKV, nm1, Dd, Kb, Vb, nullptr, 0,0,0,0, 384, 128};
  gemm11_kernel<128, 6><<<dim3(400, 1, 8), 256, 0, stream>>>(P);

  // attention: O overwrites Q in Dd
  attn_kernel<<<2048, 256, 0, stream>>>(Dd, Kb, Vb);

  // AO = mv_linear(O, wo, bo) -> R1 first plane-set (K dead)
  P = G11{Dd, WO, bo, nullptr, R1, nullptr, nullptr, nullptr, 0,0,0,0, 128, 128};
  gemm11_kernel<128, 2><<<dim3(400, 1, 8), 256, 0, stream>>>(P);

  // Xres = src + AO -> R2 (Xp dead) ; 1/nm2
  xres_kernel<<<3200, 256, 0, stream>>>(src, R1, R2, nm2);

  // XL/XR one dispatch: ct 0-3 -> XL(Dd, cols 0/64/128/192), 4-7 -> XR(R1)
  P = G11{R2, WG12, BG12, nm2, Dd, Dd, R1, R1, 0, 128, 0, 128, 512, 256};
  gemm11_kernel<128, 8><<<dim3(400, 1, 8), 256, 0, stream>>>(P);

  // GP in place over XL (Dd)
  gp_kernel<<<6400, 256, 0, stream>>>(Dd, R1);

  // Gl = mv_linear(GP, gw3, gb3) -> R1 first plane-set (XR dead)
  P = G11{Dd, WG3, gb3, nullptr, R1, nullptr, nullptr, nullptr, 0,0,0,0, 128, 128};
  gemm11_kernel<256, 2><<<dim3(400, 1, 8), 256, 0, stream>>>(P);

  // X3 = ln2a*Xres/nm2 + gna*Gl/nmg (in place in R2) ; 1/nm4
  combine_kernel<<<3200, 256, 0, stream>>>(R2, R1, ln2_a, gna, nm2, nm4);

  // H = mv_linear(LN3(X3), mw1, mb1) -> Dd ([8][N][256])
  P = G11{R2, WM1, mb1, nm4, Dd, Dd, nullptr, nullptr, 0, 128, 0, 0, 256, 256};
  gemm11_kernel<128, 4><<<dim3(400, 1, 8), 256, 0, stream>>>(P);

  // MVSiLU in place on H
  silu_kernel<<<6400, 256, 0, stream>>>(Dd, sa, sb);

  // FF = mv_linear(H, mw2, mb2) -> R1 first plane-set (Gl dead)
  P = G11{Dd, WM2, mb2, nullptr, R1, nullptr, nullptr, nullptr, 0,0,0,0, 128, 128};
  gemm11_kernel<256, 2><<<dim3(400, 1, 8), 256, 0, stream>>>(P);

  // out = ln3a*X3/nm4 + FF -> d_out fp32 interleaved (H dead)
  final_kernel<<<3200, 256, 0, stream>>>(R2, R1, ln3_a, nm4, (float*)d_out);
}

// Round 18
// 573.224 us; speedup vs baseline: 1.0521x; 1.0521x over previous
//
#include <hip/hip_runtime.h>
#include <hip/hip_bf16.h>
#include <math.h>

#define NROWS 25600
#define SEQL  25
#define EPSV  1e-6f

typedef __hip_bfloat16 bf16;
typedef __attribute__((ext_vector_type(4))) float f32x4;
typedef __attribute__((ext_vector_type(8))) short bf16x8;
typedef __attribute__((ext_vector_type(4))) short s16x4;
typedef unsigned int u32;

#define GLD16(gp_, lp_) __builtin_amdgcn_global_load_lds( \
    (const __attribute__((address_space(1))) u32*)(gp_), \
    (__attribute__((address_space(3))) u32*)(lp_), 16, 0, 0)

__device__ __forceinline__ float b2f(short s) {
  return __uint_as_float(((u32)(unsigned short)s) << 16);
}
__device__ __forceinline__ short f2b(float f) {
  __hip_bfloat16 h = __float2bfloat16(f);
  return *reinterpret_cast<short*>(&h);
}

// ---------------- Cl(3,0) geometric product (fp32) --------------------------
__device__ __forceinline__ void gprod(const float* a, const float* b, float* r) {
  const int M[8] = {0,1,2,4,3,5,6,7};
  const int P[8] = {0,1,2,4,3,5,6,7};
#pragma unroll
  for (int i = 0; i < 8; ++i) {
    const int ma = M[i];
#pragma unroll
    for (int k = 0; k < 8; ++k) {
      const int mb = M[k];
      int par = 0;
      for (int t = ma >> 1; t; t >>= 1) par += __popc(t & mb);
      const float s = (par & 1) ? -1.f : 1.f;
      r[P[ma ^ mb]] += s * a[i] * b[k];
    }
  }
}

// ---------------- gemm8e: 128x64 tile + LDS-staged coalesced epilogue -------
// A planar [8][NROWS][KT]; W [4 grades][ONW][KT] bf16 (LN fold applied).
// blockIdx.y = 64-col tile; buffer = Y[by>>1], col = yc[by>>1]+(by&1)*64.
// K-loop identical to round-13 gemm8 (proven). Epilogue: stage C in LDS
// (pitch 84 shorts = 168B -> disjoint-bank write groups), write 16B/thread
// fully-packed rows (kills the 2x HBM write amplification).
struct G8 {
  const bf16* A; const bf16* W; const float* bias; const float* invnm;
  bf16* Y0; bf16* Y1; bf16* Y2; bf16* Y3;
  int yc0, yc1, yc2, yc3; int ONW; int ONS;
};

#define OPITCH 84

template<int KT>
__global__ __launch_bounds__(256, 3) void gemm8_kernel(G8 P)
{
  __shared__ __align__(16) short As[128 * 128];
  __shared__ __align__(16) short Bs[64 * 128];
  const int tid  = threadIdx.x;
  const int lane = tid & 63;
  const int wid  = tid >> 6;
  const int z    = blockIdx.z;
  const int g    = (z == 0) ? 0 : ((z < 4) ? 1 : ((z < 7) ? 2 : 3));
  const int by   = blockIdx.y;
  const size_t n0 = (size_t)blockIdx.x * 128;
  const bf16* Ab = P.A + (size_t)z * NROWS * KT + n0 * KT;
  const bf16* Wb = P.W + ((size_t)g * P.ONW + by * 64) * KT;
  const int bufi = by >> 1;
  bf16* Yb; int yc;
  if      (bufi == 0) { Yb = P.Y0; yc = P.yc0; }
  else if (bufi == 1) { Yb = P.Y1; yc = P.yc1; }
  else if (bufi == 2) { Yb = P.Y2; yc = P.yc2; }
  else                { Yb = P.Y3; yc = P.yc3; }
  yc += (by & 1) * 64;

  f32x4 acc[4][2];
#pragma unroll
  for (int i = 0; i < 4; ++i)
#pragma unroll
    for (int j = 0; j < 2; ++j) acc[i][j] = (f32x4){0.f, 0.f, 0.f, 0.f};

  const int wm = (wid & 1) * 64;        // row half (64 rows per wave pair)
  const int wn = (wid >> 1) * 32;       // col half (32 cols per wave pair)
  const int lg  = lane >> 4;
  const int c8  = lane & 15;
  const int l15 = lane & 15;

  constexpr int NC = KT / 128;
#pragma unroll
  for (int kc = 0; kc < NC; ++kc) {
#pragma unroll
    for (int j = 0; j < 8; ++j) {
      const int row = wid * 32 + j * 4 + lg;
      const int sw = (c8 ^ (row & 7)) * 8;
      GLD16(Ab + (size_t)row * KT + kc * 128 + sw, &As[wid * 4096 + j * 512]);
    }
#pragma unroll
    for (int j = 0; j < 4; ++j) {
      const int row = wid * 16 + j * 4 + lg;
      const int sw = (c8 ^ (row & 7)) * 8;
      GLD16(Wb + (size_t)row * KT + kc * 128 + sw, &Bs[wid * 2048 + j * 512]);
    }
    __syncthreads();
#pragma unroll
    for (int ks = 0; ks < 4; ++ks) {
      bf16x8 af[4], bg[2];
#pragma unroll
      for (int i = 0; i < 4; ++i) {
        const int rA = wm + i * 16 + l15;
        af[i] = *(const bf16x8*)&As[rA * 128 + (((ks * 4 + lg) ^ (rA & 7)) * 8)];
      }
#pragma unroll
      for (int i = 0; i < 2; ++i) {
        const int rB = wn + i * 16 + l15;
        bg[i] = *(const bf16x8*)&Bs[rB * 128 + (((ks * 4 + lg) ^ (rB & 7)) * 8)];
      }
#pragma unroll
      for (int mi = 0; mi < 4; ++mi)
#pragma unroll
        for (int ni = 0; ni < 2; ++ni)
          acc[mi][ni] = __builtin_amdgcn_mfma_f32_16x16x32_bf16(af[mi], bg[ni], acc[mi][ni], 0, 0, 0);
    }
    __syncthreads();
  }

  // ---- epilogue: stage C in LDS (reuse As), then coalesced 16B writes ----
  short* Os = As;   // 128 rows x OPITCH shorts (cols 0..63 used) = 21504 B
  const int cr = lg * 4;
#pragma unroll
  for (int mi = 0; mi < 4; ++mi) {
#pragma unroll
    for (int j = 0; j < 4; ++j) {
      const int r = wm + mi * 16 + cr + j;
      const size_t n = n0 + r;
      const float sc = P.invnm ? P.invnm[n] : 1.f;
#pragma unroll
      for (int ni = 0; ni < 2; ++ni) {
        const int cl = wn + ni * 16 + l15;
        float v = acc[mi][ni][j] * sc;
        if (z == 0) v += P.bias[by * 64 + cl];
        Os[r * OPITCH + cl] = f2b(v);
      }
    }
  }
  __syncthreads();

  bf16* Yp = Yb + (size_t)z * NROWS * P.ONS + yc;
  const int wrow = tid >> 3;        // 0..31
  const int wcol = (tid & 7) * 8;   // 8 cols per thread (16B)
#pragma unroll
  for (int rr = 0; rr < 4; ++rr) {
    const int row = rr * 32 + wrow;
    const s16x4 lo = *(const s16x4*)&Os[row * OPITCH + wcol];
    const s16x4 hi = *(const s16x4*)&Os[row * OPITCH + wcol + 4];
    *(s16x4*)(Yp + (size_t)(n0 + row) * P.ONS + wcol) = lo;
    *(s16x4*)(Yp + (size_t)(n0 + row) * P.ONS + wcol + 4) = hi;
  }
}

// ---------------- weight prep: combined planar bf16 weights -----------------
__global__ __launch_bounds__(256) void wprep_all_kernel(
    const float* wq, const float* wk, const float* wv, const float* wo,
    const float* gw1, const float* gw2, const float* gw3,
    const float* mw1, const float* mw2,
    const float* ln1, const float* ln2, const float* ln3,
    bf16* WQKV, bf16* WO, bf16* WG12, bf16* WG3, bf16* WM1, bf16* WM2)
{
  const int gid = blockIdx.x * 256 + threadIdx.x;
  const float* w; const float* ln; bf16* out; int K; int idx; int planeSz; int rowOfs;
  if      (gid <  16384) { w=wq;  ln=ln1;     out=WQKV; K=128; idx=gid;        planeSz=49152; rowOfs=0;   }
  else if (gid <  32768) { w=wk;  ln=ln1;     out=WQKV; K=128; idx=gid-16384;  planeSz=49152; rowOfs=128; }
  else if (gid <  49152) { w=wv;  ln=ln1;     out=WQKV; K=128; idx=gid-32768;  planeSz=49152; rowOfs=256; }
  else if (gid <  65536) { w=wo;  ln=nullptr; out=WO;   K=128; idx=gid-49152;  planeSz=16384; rowOfs=0;   }
  else if (gid <  98304) { w=gw1; ln=ln2;     out=WG12; K=128; idx=gid-65536;  planeSz=65536; rowOfs=0;   }
  else if (gid < 131072) { w=gw2; ln=ln2;     out=WG12; K=128; idx=gid-98304;  planeSz=65536; rowOfs=256; }
  else if (gid < 163840) { w=gw3; ln=nullptr; out=WG3;  K=256; idx=gid-131072; planeSz=32768; rowOfs=0;   }
  else if (gid < 196608) { w=mw1; ln=ln3;     out=WM1;  K=128; idx=gid-163840; planeSz=32768; rowOfs=0;   }
  else                   { w=mw2; ln=nullptr; out=WM2;  K=256; idx=gid-196608; planeSz=32768; rowOfs=0;   }
  const int k = idx % K;
  const float s = ln ? ln[k] : 1.f;
  const float4 wv4 = *(const float4*)(w + (size_t)idx * 4);
  bf16* dst = out + (size_t)rowOfs * K + idx;
  dst[0 * planeSz] = __float2bfloat16(wv4.x * s);
  dst[1 * planeSz] = __float2bfloat16(wv4.y * s);
  dst[2 * planeSz] = __float2bfloat16(wv4.z * s);
  dst[3 * planeSz] = __float2bfloat16(wv4.w * s);
}

// ---------------- combined bias buffers -------------------------------------
__global__ __launch_bounds__(256) void bias_prep_kernel(
    const float* bq, const float* bk, const float* bv,
    const float* gb1, const float* gb2,
    float* BQKV, float* BG12)
{
  const int t = blockIdx.x * 256 + threadIdx.x;
  if      (t < 128) BQKV[t] = bq[t];
  else if (t < 256) BQKV[t] = bk[t - 128];
  else if (t < 384) BQKV[t] = bv[t - 256];
  else if (t < 640) BG12[t - 384] = gb1[t - 384];
  else if (t < 896) BG12[t - 384] = gb2[t - 640];
}

// ---------------- repack: src f32 [n][128][8] -> Xp bf16 planar + 1/nm1 -----
__global__ __launch_bounds__(256) void repack_kernel(
    const float* __restrict__ src, bf16* __restrict__ Xp, float* __restrict__ nminv)
{
  const int tid = threadIdx.x;
  const size_t base = ((size_t)blockIdx.x * 256 + tid) * 4;
  const size_t P = (size_t)NROWS * 128;
  float v[4][8];
  const float4* sp = (const float4*)(src + base * 8);
  float part = 0.f;
#pragma unroll
  for (int e = 0; e < 4; ++e) {
    const float4 a = sp[e * 2], b = sp[e * 2 + 1];
    v[e][0]=a.x; v[e][1]=a.y; v[e][2]=a.z; v[e][3]=a.w;
    v[e][4]=b.x; v[e][5]=b.y; v[e][6]=b.z; v[e][7]=b.w;
    float ss = 0.f;
#pragma unroll
    for (int p = 0; p < 8; ++p) ss += v[e][p] * v[e][p];
    part += sqrtf(ss);
  }
#pragma unroll
  for (int p = 0; p < 8; ++p) {
    s16x4 o;
#pragma unroll
    for (int e = 0; e < 4; ++e) o[e] = f2b(v[e][p]);
    *(s16x4*)(Xp + p * P + base) = o;
  }
#pragma unroll
  for (int off = 1; off < 32; off <<= 1) part += __shfl_xor(part, off);
  if ((tid & 31) == 0) nminv[base >> 7] = 1.f / (part / 128.f + EPSV);
}

// ---------------- attention: 1 wave per (b,h); MFMA QK^T, in-reg softmax ----
__global__ __launch_bounds__(256) void attn_kernel(
    bf16* __restrict__ Q, const bf16* __restrict__ K, const bf16* __restrict__ V)
{
  __shared__ float Pld[4][32 * 36];
  const int tid  = threadIdx.x;
  const int lane = tid & 63;
  const int wid  = tid >> 6;
  const int job  = blockIdx.x * 4 + wid;
  const int b    = job >> 3;
  const int h    = job & 7;
  const size_t PS = (size_t)NROWS * 128;
  const int rowbase = b * SEQL;
  const int l15 = lane & 15;
  const int lg  = lane >> 4;

  f32x4 acc[2][2];
#pragma unroll
  for (int si = 0; si < 2; ++si)
#pragma unroll
    for (int ti = 0; ti < 2; ++ti) acc[si][ti] = (f32x4){0.f,0.f,0.f,0.f};

#pragma unroll
  for (int ks = 0; ks < 4; ++ks) {
    const int f = ks * 32 + lg * 8;
    const int p = f >> 4, d = f & 15;
    bf16x8 aq[2], bk[2];
#pragma unroll
    for (int si = 0; si < 2; ++si) {
      int s = si * 16 + l15; if (s > 24) s = 24;
      aq[si] = *(const bf16x8*)(Q + (size_t)p * PS + (size_t)(rowbase + s) * 128 + h * 16 + d);
    }
#pragma unroll
    for (int ti = 0; ti < 2; ++ti) {
      int t = ti * 16 + l15; if (t > 24) t = 24;
      bk[ti] = *(const bf16x8*)(K + (size_t)p * PS + (size_t)(rowbase + t) * 128 + h * 16 + d);
    }
#pragma unroll
    for (int si = 0; si < 2; ++si)
#pragma unroll
      for (int ti = 0; ti < 2; ++ti)
        acc[si][ti] = __builtin_amdgcn_mfma_f32_16x16x32_bf16(aq[si], bk[ti], acc[si][ti], 0, 0, 0);
  }

  const float scale = 0.08838834764831845f;
  float pv[2][2][4];
#pragma unroll
  for (int si = 0; si < 2; ++si)
#pragma unroll
    for (int ti = 0; ti < 2; ++ti)
#pragma unroll
      for (int r = 0; r < 4; ++r) {
        float v = acc[si][ti][r] * scale;
        if (ti * 16 + l15 > 24) v = -1e30f;
        pv[si][ti][r] = v;
      }
#pragma unroll
  for (int si = 0; si < 2; ++si)
#pragma unroll
    for (int r = 0; r < 4; ++r) {
      float m = fmaxf(pv[si][0][r], pv[si][1][r]);
#pragma unroll
      for (int off = 1; off < 16; off <<= 1) m = fmaxf(m, __shfl_xor(m, off));
      const float e0 = __expf(pv[si][0][r] - m);
      const float e1 = __expf(pv[si][1][r] - m);
      float sum = e0 + e1;
#pragma unroll
      for (int off = 1; off < 16; off <<= 1) sum += __shfl_xor(sum, off);
      const float inv = 1.f / sum;
      pv[si][0][r] = e0 * inv;
      pv[si][1][r] = e1 * inv;
    }

  float* Pw = &Pld[wid][0];
#pragma unroll
  for (int si = 0; si < 2; ++si)
#pragma unroll
    for (int ti = 0; ti < 2; ++ti)
#pragma unroll
      for (int r = 0; r < 4; ++r)
        Pw[(si * 16 + lg * 4 + r) * 36 + ti * 16 + l15] = pv[si][ti][r];
  __syncthreads();

  const int p2 = lane >> 3;
  const int d2 = (lane & 7) * 2;
  const bf16* vb = V + (size_t)p2 * PS + (size_t)rowbase * 128 + h * 16 + d2;
  float vlo[32], vhi[32];
#pragma unroll
  for (int t = 0; t < SEQL; ++t) {
    const __hip_bfloat162 vv = *(const __hip_bfloat162*)(vb + (size_t)t * 128);
    vlo[t] = __bfloat162float(vv.x);
    vhi[t] = __bfloat162float(vv.y);
  }
#pragma unroll
  for (int t = SEQL; t < 32; ++t) { vlo[t] = 0.f; vhi[t] = 0.f; }

  bf16* ob = Q + (size_t)p2 * PS + (size_t)rowbase * 128 + h * 16 + d2;
  for (int s = 0; s < SEQL; ++s) {
    const float4* pr = reinterpret_cast<const float4*>(&Pld[wid][s * 36]);
    float a0 = 0.f, a1 = 0.f;
#pragma unroll
    for (int t4 = 0; t4 < 8; ++t4) {
      const float4 pq = pr[t4];
      a0 += pq.x * vlo[t4*4+0] + pq.y * vlo[t4*4+1] + pq.z * vlo[t4*4+2] + pq.w * vlo[t4*4+3];
      a1 += pq.x * vhi[t4*4+0] + pq.y * vhi[t4*4+1] + pq.z * vhi[t4*4+2] + pq.w * vhi[t4*4+3];
    }
    __hip_bfloat162 o2;
    o2.x = __float2bfloat16(a0);
    o2.y = __float2bfloat16(a1);
    *(__hip_bfloat162*)(ob + (size_t)s * 128) = o2;
  }
}

// ---------------- xres = src + AO (4-wide) + 1/nm2 --------------------------
__global__ __launch_bounds__(256) void xres_kernel(
    const float* __restrict__ src, const bf16* __restrict__ AO,
    bf16* __restrict__ X, float* __restrict__ nminv)
{
  const int tid = threadIdx.x;
  const size_t base = ((size_t)blockIdx.x * 256 + tid) * 4;
  const size_t P = (size_t)NROWS * 128;
  float v[4][8];
  const float4* sp = (const float4*)(src + base * 8);
#pragma unroll
  for (int e = 0; e < 4; ++e) {
    const float4 a = sp[e * 2], b = sp[e * 2 + 1];
    v[e][0]=a.x; v[e][1]=a.y; v[e][2]=a.z; v[e][3]=a.w;
    v[e][4]=b.x; v[e][5]=b.y; v[e][6]=b.z; v[e][7]=b.w;
  }
  float part = 0.f;
  float ss[4] = {0.f, 0.f, 0.f, 0.f};
#pragma unroll
  for (int p = 0; p < 8; ++p) {
    const s16x4 av = *(const s16x4*)(AO + p * P + base);
    s16x4 o;
#pragma unroll
    for (int e = 0; e < 4; ++e) {
      v[e][p] += b2f(av[e]);
      o[e] = f2b(v[e][p]);
      ss[e] += v[e][p] * v[e][p];
    }
    *(s16x4*)(X + p * P + base) = o;
  }
#pragma unroll
  for (int e = 0; e < 4; ++e) part += sqrtf(ss[e]);
#pragma unroll
  for (int off = 1; off < 32; off <<= 1) part += __shfl_xor(part, off);
  if ((tid & 31) == 0) nminv[base >> 7] = 1.f / (part / 128.f + EPSV);
}

// ---------------- GP elementwise (4-wide, in place over XL) -----------------
__global__ __launch_bounds__(256) void gp_kernel(
    bf16* __restrict__ XL, const bf16* __restrict__ XR)
{
  const size_t base = ((size_t)blockIdx.x * 256 + threadIdx.x) * 4;
  const size_t P = (size_t)NROWS * 256;
  s16x4 av[8], bv[8], rv[8];
#pragma unroll
  for (int p = 0; p < 8; ++p) {
    av[p] = *(const s16x4*)(XL + p * P + base);
    bv[p] = *(const s16x4*)(XR + p * P + base);
  }
#pragma unroll
  for (int e = 0; e < 4; ++e) {
    float a[8], b[8], r[8] = {0.f,0.f,0.f,0.f,0.f,0.f,0.f,0.f};
#pragma unroll
    for (int p = 0; p < 8; ++p) { a[p] = b2f(av[p][e]); b[p] = b2f(bv[p][e]); }
    gprod(a, b, r);
#pragma unroll
    for (int p = 0; p < 8; ++p) rv[p][e] = f2b(r[p]);
  }
#pragma unroll
  for (int p = 0; p < 8; ++p) *(s16x4*)(XL + p * P + base) = rv[p];
}

// ---- x3 = ln2a*Xres/nm2 + gna*Gl/nmg (4-wide, shfl norms, in place) --------
__global__ __launch_bounds__(256) void combine_kernel(
    bf16* __restrict__ X, const bf16* __restrict__ Gl,
    const float* __restrict__ ln2a, const float* __restrict__ gna,
    const float* __restrict__ nm2inv, float* __restrict__ nm4inv)
{
  const int tid = threadIdx.x;
  const size_t base = ((size_t)blockIdx.x * 256 + tid) * 4;
  const size_t P = (size_t)NROWS * 128;
  const size_t n = base >> 7;
  const int c = (int)(base & 127);

  float gv[4][8];
  float ssg[4] = {0.f,0.f,0.f,0.f};
#pragma unroll
  for (int p = 0; p < 8; ++p) {
    const s16x4 g4 = *(const s16x4*)(Gl + p * P + base);
#pragma unroll
    for (int e = 0; e < 4; ++e) { gv[e][p] = b2f(g4[e]); ssg[e] += gv[e][p] * gv[e][p]; }
  }
  float partg = sqrtf(ssg[0]) + sqrtf(ssg[1]) + sqrtf(ssg[2]) + sqrtf(ssg[3]);
#pragma unroll
  for (int off = 1; off < 32; off <<= 1) partg += __shfl_xor(partg, off);
  const float invg = 1.f / (partg / 128.f + EPSV);

  const float n2 = nm2inv[n];
  float s2[4], sg[4];
#pragma unroll
  for (int e = 0; e < 4; ++e) { s2[e] = ln2a[c + e] * n2; sg[e] = gna[c + e] * invg; }

  float ss[4] = {0.f,0.f,0.f,0.f};
#pragma unroll
  for (int p = 0; p < 8; ++p) {
    const s16x4 x4 = *(const s16x4*)(X + p * P + base);
    s16x4 o;
#pragma unroll
    for (int e = 0; e < 4; ++e) {
      const float v = s2[e] * b2f(x4[e]) + sg[e] * gv[e][p];
      o[e] = f2b(v);
      ss[e] += v * v;
    }
    *(s16x4*)(X + p * P + base) = o;
  }
  float part = sqrtf(ss[0]) + sqrtf(ss[1]) + sqrtf(ss[2]) + sqrtf(ss[3]);
#pragma unroll
  for (int off = 1; off < 32; off <<= 1) part += __shfl_xor(part, off);
  if ((tid & 31) == 0) nm4inv[n] = 1.f / (part / 128.f + EPSV);
}

// ---------------- MVSiLU (4-wide, in place) ---------------------------------
__global__ __launch_bounds__(256) void silu_kernel(
    bf16* __restrict__ H, const float* __restrict__ sa, const float* __restrict__ sb)
{
  const size_t base = ((size_t)blockIdx.x * 256 + threadIdx.x) * 4;
  const int c = (int)(base & 255);
  const size_t P = (size_t)NROWS * 256;
  s16x4 hv[8];
#pragma unroll
  for (int p = 0; p < 8; ++p) hv[p] = *(const s16x4*)(H + p * P + base);
#pragma unroll
  for (int e = 0; e < 4; ++e) {
    float v[8];
#pragma unroll
    for (int p = 0; p < 8; ++p) v[p] = b2f(hv[p][e]);
    const float i0 = v[0];
    const float i1 = v[1]*v[1] + v[2]*v[2] + v[3]*v[3];
    const float i2 = v[4]*v[4] + v[5]*v[5] + v[6]*v[6];
    const float i3 = v[7]*v[7];
    const int cc = c + e;
    const float g0 = 1.f / (1.f + __expf(-(sa[cc*4+0]*i0 + sb[cc*4+0])));
    const float g1 = 1.f / (1.f + __expf(-(sa[cc*4+1]*i1 + sb[cc*4+1])));
    const float g2 = 1.f / (1.f + __expf(-(sa[cc*4+2]*i2 + sb[cc*4+2])));
    const float g3 = 1.f / (1.f + __expf(-(sa[cc*4+3]*i3 + sb[cc*4+3])));
    v[0]*=g0; v[1]*=g1; v[2]*=g1; v[3]*=g1; v[4]*=g2; v[5]*=g2; v[6]*=g2; v[7]*=g3;
#pragma unroll
    for (int p = 0; p < 8; ++p) hv[p][e] = f2b(v[p]);
  }
#pragma unroll
  for (int p = 0; p < 8; ++p) *(s16x4*)(H + p * P + base) = hv[p];
}

// ---------------- final: out = ln3a*X3/nm4 + FF (4-wide, coalesced) ---------
__global__ __launch_bounds__(256) void final_kernel(
    const bf16* __restrict__ X3, const bf16* __restrict__ FF,
    const float* __restrict__ ln3a, const float* __restrict__ nm4inv,
    float* __restrict__ out)
{
  const size_t base = ((size_t)blockIdx.x * 256 + threadIdx.x) * 4;
  const int c = (int)(base & 127);
  const size_t n = base >> 7;
  const size_t P = (size_t)NROWS * 128;
  const float nm = nm4inv[n];
  float o[4][8];
#pragma unroll
  for (int p = 0; p < 8; ++p) {
    const s16x4 x4 = *(const s16x4*)(X3 + p * P + base);
    const s16x4 f4 = *(const s16x4*)(FF + p * P + base);
#pragma unroll
    for (int e = 0; e < 4; ++e)
      o[e][p] = ln3a[c + e] * nm * b2f(x4[e]) + b2f(f4[e]);
  }
  float4* op = (float4*)(out + base * 8);
#pragma unroll
  for (int e = 0; e < 4; ++e) {
    float4 lo, hi;
    lo.x=o[e][0]; lo.y=o[e][1]; lo.z=o[e][2]; lo.w=o[e][3];
    hi.x=o[e][4]; hi.y=o[e][5]; hi.z=o[e][6]; hi.w=o[e][7];
    op[e * 2] = lo;
    op[e * 2 + 1] = hi;
  }
}

// ---------------- launch ----------------------------------------------------
extern "C" void kernel_launch(void* const* d_in, const int* in_sizes, int n_in,
                              void* d_out, int out_size, void* d_ws, size_t ws_size,
                              hipStream_t stream) {
  (void)in_sizes; (void)n_in; (void)out_size; (void)ws_size;
  const float* src   = (const float*)d_in[0];
  const float* ln1_a = (const float*)d_in[1];
  const float* ln2_a = (const float*)d_in[2];
  const float* ln3_a = (const float*)d_in[3];
  const float* wq = (const float*)d_in[4];  const float* bq = (const float*)d_in[5];
  const float* wk = (const float*)d_in[6];  const float* bk = (const float*)d_in[7];
  const float* wv = (const float*)d_in[8];  const float* bv = (const float*)d_in[9];
  const float* wo = (const float*)d_in[10]; const float* bo = (const float*)d_in[11];
  const float* gw1 = (const float*)d_in[12]; const float* gb1 = (const float*)d_in[13];
  const float* gw2 = (const float*)d_in[14]; const float* gb2 = (const float*)d_in[15];
  const float* gw3 = (const float*)d_in[16]; const float* gb3 = (const float*)d_in[17];
  const float* gna = (const float*)d_in[18];
  const float* mw1 = (const float*)d_in[19]; const float* mb1 = (const float*)d_in[20];
  const float* sa  = (const float*)d_in[21]; const float* sb  = (const float*)d_in[22];
  const float* mw2 = (const float*)d_in[23]; const float* mb2 = (const float*)d_in[24];

  char* ws = (char*)d_ws;
  const size_t P128 = (size_t)NROWS * 128;
  const size_t PSET = 8 * P128;               // one full [8][N][128] plane-set
  bf16* R1 = (bf16*)ws;                       // 104,857,600 B = 2 plane-sets
  bf16* R2 = (bf16*)(ws + 104857600);         //  52,428,800 B = 1 plane-set
  bf16* WQKV = (bf16*)(ws + 157286400);       // [4][384][128]
  bf16* WO   = WQKV + 196608;                 // [4][128][128]
  bf16* WG12 = WO   + 65536;                  // [4][512][128]
  bf16* WG3  = WG12 + 262144;                 // [4][128][256]
  bf16* WM1  = WG3  + 131072;                 // [4][256][128]
  bf16* WM2  = WM1  + 131072;                 // [4][128][256]
  float* BQKV = (float*)(ws + 159121408);     // 384
  float* BG12 = BQKV + 384;                   // 512
  float* nm1  = BG12 + 512;
  float* nm2  = nm1 + NROWS;
  float* nm4  = nm2 + NROWS;

  bf16* Dd = (bf16*)d_out;   // scratch: Q/O, then XL/GP/H; final fp32 out
  bf16* Kb = R1;             // K plane-set
  bf16* Vb = R1 + PSET;      // V plane-set (disjoint)

  wprep_all_kernel<<<896, 256, 0, stream>>>(
      wq, wk, wv, wo, gw1, gw2, gw3, mw1, mw2, ln1_a, ln2_a, ln3_a,
      WQKV, WO, WG12, WG3, WM1, WM2);
  bias_prep_kernel<<<4, 256, 0, stream>>>(bq, bk, bv, gb1, gb2, BQKV, BG12);

  // repack src -> Xp (R2) + 1/nm1
  repack_kernel<<<3200, 256, 0, stream>>>(src, R2, nm1);

  G8 P{};
  // QKV one dispatch: by 0-1 -> Q(Dd), 2-3 -> K(Kb), 4-5 -> V(Vb)
  P = G8{R2, WQKV, BQKV, nm1, Dd, Kb, Vb, nullptr, 0,0,0,0, 384, 128};
  gemm8_kernel<128><<<dim3(200, 6, 8), 256, 0, stream>>>(P);

  // attention: O overwrites Q in Dd
  attn_kernel<<<2048, 256, 0, stream>>>(Dd, Kb, Vb);

  // AO = mv_linear(O, wo, bo) -> R1 first plane-set (K dead)
  P = G8{Dd, WO, bo, nullptr, R1, nullptr, nullptr, nullptr, 0,0,0,0, 128, 128};
  gemm8_kernel<128><<<dim3(200, 2, 8), 256, 0, stream>>>(P);

  // Xres = src + AO -> R2 (Xp dead) ; 1/nm2
  xres_kernel<<<3200, 256, 0, stream>>>(src, R1, R2, nm2);

  // XL/XR one dispatch: by 0-3 -> XL(Dd, cols 0/64/128/192), 4-7 -> XR(R1)
  P = G8{R2, WG12, BG12, nm2, Dd, Dd, R1, R1, 0, 128, 0, 128, 512, 256};
  gemm8_kernel<128><<<dim3(200, 8, 8), 256, 0, stream>>>(P);

  // GP in place over XL (Dd)
  gp_kernel<<<6400, 256, 0, stream>>>(Dd, R1);

  // Gl = mv_linear(GP, gw3, gb3) -> R1 first plane-set (XR dead)
  P = G8{Dd, WG3, gb3, nullptr, R1, nullptr, nullptr, nullptr, 0,0,0,0, 128, 128};
  gemm8_kernel<256><<<dim3(200, 2, 8), 256, 0, stream>>>(P);

  // X3 = ln2a*Xres/nm2 + gna*Gl/nmg (in place in R2) ; 1/nm4
  combine_kernel<<<3200, 256, 0, stream>>>(R2, R1, ln2_a, gna, nm2, nm4);

  // H = mv_linear(LN3(X3), mw1, mb1) -> Dd ([8][N][256])
  P = G8{R2, WM1, mb1, nm4, Dd, Dd, nullptr, nullptr, 0, 128, 0, 0, 256, 256};
  gemm8_kernel<128><<<dim3(200, 4, 8), 256, 0, stream>>>(P);

  // MVSiLU in place on H
  silu_kernel<<<6400, 256, 0, stream>>>(Dd, sa, sb);

  // FF = mv_linear(H, mw2, mb2) -> R1 first plane-set (Gl dead)
  P = G8{Dd, WM2, mb2, nullptr, R1, nullptr, nullptr, nullptr, 0,0,0,0, 128, 128};
  gemm8_kernel<256><<<dim3(200, 2, 8), 256, 0, stream>>>(P);

  // out = ln3a*X3/nm4 + FF -> d_out fp32 interleaved (H dead)
  final_kernel<<<3200, 256, 0, stream>>>(R2, R1, ln3_a, nm4, (float*)d_out);
}